// Round 4
// baseline (1110.088 us; speedup 1.0000x reference)
//
#include <hip/hip_runtime.h>
#include <hip/hip_bf16.h>
#include <stdint.h>

// Sparse MoE FFN: N=32768 tokens, D=H=1024, E=8, top-2, fp32 in/out.
// Pipeline: fp32 gate+top2 (LDS bucketing into 16 (expert,k) classes, fused
// x->bf16) -> bf16 MFMA GEMM1 (relu) -> GEMM2a (k=0, plain store = full out
// coverage) -> GEMM2b (k=1, unique-writer non-atomic RMW add).
// GEMMs: 256x256 tile, BK=32, double-buffered LDS (64 KB), 8 waves,
// prefetch-next-tile-before-compute (T3 minimum 2-phase recipe + T5 setprio).

#define NTOK  32768
#define DMODEL 1024
#define HDIM   1024
#define NEXP      8
#define NCLS     16   // (expert, k) classes
#define BKT      32   // K per LDS tile
#define NT       (DMODEL / BKT)

typedef __bf16 bf16;
typedef __bf16 bf16x4 __attribute__((ext_vector_type(4)));
typedef __bf16 bf16x8 __attribute__((ext_vector_type(8)));
typedef float  f32x4  __attribute__((ext_vector_type(4)));

// ---- workspace layout (bytes), identical to round 3 (known to fit) ----
static constexpr size_t WS_CNT    = 0;                                        // 16 int
static constexpr size_t WS_OFFS   = 256;                                      // 16 int
static constexpr size_t WS_BUCKET = 512;                                      // [NCLS][NTOK] int (entry = tok*2+k)
static constexpr size_t WS_TOPKS  = WS_BUCKET + (size_t)NCLS * NTOK * 4;      // [NTOK*2] float
static constexpr size_t WS_XB     = WS_TOPKS + (size_t)NTOK * 2 * 4;          // x in bf16 [NTOK][D]
static constexpr size_t WS_W1T    = WS_XB  + (size_t)NTOK * DMODEL * 2;       // w1^T bf16 [E][H][D]
static constexpr size_t WS_W2T    = WS_W1T + (size_t)NEXP * DMODEL * HDIM * 2;// w2^T bf16 [E][D][H]
static constexpr size_t WS_H      = WS_W2T + (size_t)NEXP * HDIM * DMODEL * 2;// H bf16 [2N+128][H]
static constexpr size_t WS_END    = WS_H   + (size_t)(2 * NTOK + 128) * HDIM * 2; // ~227 MiB

// async global->LDS, 16B per lane. LDS dest is wave-uniform base + lane*16.
__device__ __forceinline__ void gload16(const void* g, void* l) {
  __builtin_amdgcn_global_load_lds(
      (const __attribute__((address_space(1))) unsigned int*)(uintptr_t)g,
      (__attribute__((address_space(3))) unsigned int*)(uintptr_t)l,
      16, 0, 0);
}

// ---------------- gating: fp32 scores, exact top-2, LDS-aggregated buckets ----
__global__ __launch_bounds__(256) void gate_kernel(
    const float* __restrict__ x, const float* __restrict__ gw,
    const float* __restrict__ gb, int* __restrict__ cnt,
    int* __restrict__ bucket, float* __restrict__ topks,
    bf16* __restrict__ xb)
{
  __shared__ int lcnt[NCLS];
  __shared__ int lbase[NCLS];
  __shared__ short ti_i1[64], ti_i2[64], ti_r1[64], ti_r2[64];

  const int t = threadIdx.x;
  if (t < NCLS) lcnt[t] = 0;
  __syncthreads();

  const int lane = t & 63;
  const int wv   = t >> 6;
  const int t0   = blockIdx.x * 64;

  for (int i = 0; i < 16; ++i) {
    const int tt  = wv * 16 + i;
    const int tok = t0 + tt;
    const float4* xr4 = (const float4*)(x + (size_t)tok * DMODEL);
    bf16x4*       xbr = (bf16x4*)(xb + (size_t)tok * DMODEL);

    float sc[NEXP];
#pragma unroll
    for (int e = 0; e < NEXP; ++e) sc[e] = 0.f;

#pragma unroll
    for (int it = 0; it < 4; ++it) {
      const int q = it * 64 + lane;          // float4 index within the row
      float4 v = xr4[q];
      bf16x4 o = { (bf16)v.x, (bf16)v.y, (bf16)v.z, (bf16)v.w };
      xbr[q] = o;                            // fused fp32->bf16 conversion
      const float* g = gw + (size_t)q * 4 * NEXP;
      const float vv[4] = { v.x, v.y, v.z, v.w };
#pragma unroll
      for (int j = 0; j < 4; ++j)
#pragma unroll
        for (int e = 0; e < NEXP; ++e)
          sc[e] += vv[j] * g[j * NEXP + e];
    }
#pragma unroll
    for (int e = 0; e < NEXP; ++e) {
      float a = sc[e];
#pragma unroll
      for (int off = 32; off; off >>= 1) a += __shfl_xor(a, off);
      sc[e] = a + gb[e];
    }

    if (lane == 0) {
      // strict > keeps the lowest index on ties == lax.top_k semantics
      int i1 = 0; float s1 = sc[0];
#pragma unroll
      for (int e = 1; e < NEXP; ++e) if (sc[e] > s1) { s1 = sc[e]; i1 = e; }
      int i2 = (i1 == 0) ? 1 : 0; float s2 = sc[i2];
#pragma unroll
      for (int e = 0; e < NEXP; ++e)
        if (e != i1 && sc[e] > s2) { s2 = sc[e]; i2 = e; }
      ti_i1[tt] = (short)i1; ti_r1[tt] = (short)atomicAdd(&lcnt[i1 * 2 + 0], 1);
      ti_i2[tt] = (short)i2; ti_r2[tt] = (short)atomicAdd(&lcnt[i2 * 2 + 1], 1);
      topks[tok * 2]     = s1;
      topks[tok * 2 + 1] = s2;
    }
  }
  __syncthreads();
  if (t < NCLS) lbase[t] = atomicAdd(&cnt[t], lcnt[t]);
  __syncthreads();
  if (t < 128) {
    const int tt = t >> 1, k = t & 1;
    const int c  = k ? (ti_i2[tt] * 2 + 1) : (ti_i1[tt] * 2);
    const int r  = k ? ti_r2[tt] : ti_r1[tt];
    bucket[c * NTOK + lbase[c] + r] = (t0 + tt) * 2 + k;
  }
}

__global__ void scan_kernel(const int* __restrict__ cnt, int* __restrict__ offs) {
  if (threadIdx.x == 0) {
    int r = 0;
    for (int c = 0; c < NCLS; ++c) { offs[c] = r; r += cnt[c]; }
  }
}

// w[e][k][n] fp32 -> wt[e][n][k] bf16 (transpose so GEMM B-frags are K-contiguous)
__global__ __launch_bounds__(256) void cvt_wt_kernel(
    const float* __restrict__ w, bf16* __restrict__ wt)
{
  __shared__ float tile[32][33];
  const int e  = blockIdx.y;
  const int tk = (blockIdx.x >> 5) * 32;  // source row (k) base
  const int tn = (blockIdx.x & 31) * 32;  // source col (n) base
  const int r  = threadIdx.x >> 3, c4 = (threadIdx.x & 7) * 4;
  const float* we = w + (size_t)e * DMODEL * HDIM;
  float4 v = *(const float4*)&we[(size_t)(tk + r) * 1024 + tn + c4];
  tile[r][c4 + 0] = v.x; tile[r][c4 + 1] = v.y;
  tile[r][c4 + 2] = v.z; tile[r][c4 + 3] = v.w;
  __syncthreads();
  bf16x4 o = { (bf16)tile[c4 + 0][r], (bf16)tile[c4 + 1][r],
               (bf16)tile[c4 + 2][r], (bf16)tile[c4 + 3][r] };
  *(bf16x4*)&wt[(size_t)e * DMODEL * HDIM + (size_t)(tn + r) * 1024 + tk + c4] = o;
}

// ---- shared 256x256 K-loop macro pieces (BK=32, dbuf, prefetch-early) ----
// Wave layout: 8 waves = 2M x 4N; per-wave output 128 rows x 64 cols.
// A LDS [256 rows][32 k], B LDS [256 cols][32 k]; 16 KB each, x2 dbuf = 64 KB.

#define GEMM_STAGE(BUF, KO)                                                   \
  do {                                                                        \
    gload16(aPtr0 + (KO), &As[BUF][t * 8]);                                   \
    gload16(aPtr1 + (KO), &As[BUF][4096 + t * 8]);                            \
    gload16(bPtr0 + (KO), &Bs[BUF][t * 8]);                                   \
    gload16(bPtr1 + (KO), &Bs[BUF][4096 + t * 8]);                            \
  } while (0)

#define GEMM_COMPUTE(BUF)                                                     \
  do {                                                                        \
    bf16x8 afr[8], bfr[4];                                                    \
    _Pragma("unroll")                                                         \
    for (int m = 0; m < 8; ++m)                                               \
      afr[m] = *(const bf16x8*)&As[BUF][(wrb + m * 16 + fr) * BKT + kg * 8];  \
    _Pragma("unroll")                                                         \
    for (int nn = 0; nn < 4; ++nn)                                            \
      bfr[nn] = *(const bf16x8*)&Bs[BUF][(wcb + nn * 16 + fr) * BKT + kg * 8];\
    __builtin_amdgcn_s_setprio(1);                                            \
    _Pragma("unroll")                                                         \
    for (int m = 0; m < 8; ++m)                                               \
      _Pragma("unroll")                                                       \
      for (int nn = 0; nn < 4; ++nn)                                          \
        acc[m][nn] = __builtin_amdgcn_mfma_f32_16x16x32_bf16(                 \
            afr[m], bfr[nn], acc[m][nn], 0, 0, 0);                            \
    __builtin_amdgcn_s_setprio(0);                                            \
  } while (0)

// ---------------- GEMM1: H = relu(X[bucket] @ W1 + b1), bf16 out ----------------
__global__ __launch_bounds__(512, 2) void gemm1_kernel(
    const bf16* __restrict__ xb, const bf16* __restrict__ w1t,
    const float* __restrict__ b1, const int* __restrict__ cnt,
    const int* __restrict__ offs, const int* __restrict__ bucket,
    bf16* __restrict__ Hbuf)
{
  const int c  = blockIdx.x >> 7;           // class (e,k)
  const int e  = c >> 1;
  const int rb = blockIdx.x & 127;
  const int n  = cnt[c];
  if (rb * 256 >= n) return;
  const int cb = blockIdx.y;                // 256-col block (0..3)

  __shared__ bf16 As[2][256 * BKT];
  __shared__ bf16 Bs[2][256 * BKT];

  const int t  = threadIdx.x;
  // staging coords: thread t fills rows (t>>2) and 128+(t>>2), 16B at col (t&3)*16
  const int sr = t >> 2, sc8 = (t & 3) * 8;
  int p1 = rb * 256 + sr;       if (p1 >= n) p1 = n - 1;
  int p2 = rb * 256 + 128 + sr; if (p2 >= n) p2 = n - 1;
  const int ent1 = bucket[c * NTOK + p1];
  const int ent2 = bucket[c * NTOK + p2];
  const bf16* aPtr0 = xb + (size_t)(ent1 >> 1) * DMODEL + sc8;   // gathered rows
  const bf16* aPtr1 = xb + (size_t)(ent2 >> 1) * DMODEL + sc8;
  const bf16* bPtr0 = w1t + (size_t)e * DMODEL * HDIM
                    + (size_t)(cb * 256 + sr) * DMODEL + sc8;
  const bf16* bPtr1 = bPtr0 + (size_t)128 * DMODEL;

  const int lane = t & 63, wid = t >> 6;
  const int wrb = (wid >> 2) * 128;         // wave row base (2 M-waves)
  const int wcb = (wid & 3) * 64;           // wave col base (4 N-waves)
  const int fr = lane & 15, kg = lane >> 4;

  f32x4 acc[8][4];
#pragma unroll
  for (int m = 0; m < 8; ++m)
#pragma unroll
    for (int nn = 0; nn < 4; ++nn) acc[m][nn] = (f32x4){0.f, 0.f, 0.f, 0.f};

  // prologue: tile 0 -> buf 0
  GEMM_STAGE(0, 0);
  asm volatile("s_waitcnt vmcnt(0)" ::: "memory");
  __syncthreads();

  for (int kt = 0; kt < NT - 1; ++kt) {
    const int cur = kt & 1;
    GEMM_STAGE(cur ^ 1, (kt + 1) * BKT);    // prefetch next tile (other buf)
    GEMM_COMPUTE(cur);                      // compute current (overlaps flight)
    __syncthreads();                        // drains vmcnt+lgkm, releases bufs
  }
  GEMM_COMPUTE((NT - 1) & 1);

  // epilogue: bias + relu -> H[slot][col] bf16. C/D: col=lane&15, row=kg*4+reg.
  const int slot0 = offs[c];
  float bias[4]; int bcol[4];
#pragma unroll
  for (int nn = 0; nn < 4; ++nn) {
    bcol[nn] = cb * 256 + wcb + nn * 16 + fr;
    bias[nn] = b1[e * HDIM + bcol[nn]];
  }
#pragma unroll
  for (int m = 0; m < 8; ++m)
#pragma unroll
    for (int j = 0; j < 4; ++j) {
      const int p = rb * 256 + wrb + m * 16 + kg * 4 + j;
      if (p < n) {
        bf16* hrow = Hbuf + (size_t)(slot0 + p) * HDIM;
#pragma unroll
        for (int nn = 0; nn < 4; ++nn) {
          float v = acc[m][nn][j] + bias[nn];
          hrow[bcol[nn]] = (bf16)(v > 0.f ? v : 0.f);
        }
      }
    }
}

// -------- GEMM2: kbit=0: out[tok] = s*(H@W2+b2) (full coverage, plain store);
// kbit=1: out[tok] += ... (unique writer per (tok,col) within the launch). ----
__global__ __launch_bounds__(512, 2) void gemm2_kernel(
    const bf16* __restrict__ Hbuf, const bf16* __restrict__ w2t,
    const float* __restrict__ b2, const int* __restrict__ cnt,
    const int* __restrict__ offs, const int* __restrict__ bucket,
    const float* __restrict__ topks, float* __restrict__ out, int kbit)
{
  const int e  = blockIdx.x >> 7;
  const int c  = e * 2 + kbit;              // class
  const int rb = blockIdx.x & 127;
  const int n  = cnt[c];
  if (rb * 256 >= n) return;
  const int cb = blockIdx.y;

  __shared__ bf16 As[2][256 * BKT];
  __shared__ bf16 Bs[2][256 * BKT];

  const int t  = threadIdx.x;
  const int sr = t >> 2, sc8 = (t & 3) * 8;
  const int slot0 = offs[c];
  int p1 = rb * 256 + sr;       if (p1 >= n) p1 = n - 1;   // clamp: no slack needed
  int p2 = rb * 256 + 128 + sr; if (p2 >= n) p2 = n - 1;
  const bf16* aPtr0 = Hbuf + (size_t)(slot0 + p1) * HDIM + sc8;
  const bf16* aPtr1 = Hbuf + (size_t)(slot0 + p2) * HDIM + sc8;
  const bf16* bPtr0 = w2t + (size_t)e * HDIM * DMODEL
                    + (size_t)(cb * 256 + sr) * HDIM + sc8;
  const bf16* bPtr1 = bPtr0 + (size_t)128 * HDIM;

  const int lane = t & 63, wid = t >> 6;
  const int wrb = (wid >> 2) * 128;
  const int wcb = (wid & 3) * 64;
  const int fr = lane & 15, kg = lane >> 4;

  f32x4 acc[8][4];
#pragma unroll
  for (int m = 0; m < 8; ++m)
#pragma unroll
    for (int nn = 0; nn < 4; ++nn) acc[m][nn] = (f32x4){0.f, 0.f, 0.f, 0.f};

  GEMM_STAGE(0, 0);
  asm volatile("s_waitcnt vmcnt(0)" ::: "memory");
  __syncthreads();

  for (int kt = 0; kt < NT - 1; ++kt) {
    const int cur = kt & 1;
    GEMM_STAGE(cur ^ 1, (kt + 1) * BKT);
    GEMM_COMPUTE(cur);
    __syncthreads();
  }
  GEMM_COMPUTE((NT - 1) & 1);

  float bias[4]; int bcol[4];
#pragma unroll
  for (int nn = 0; nn < 4; ++nn) {
    bcol[nn] = cb * 256 + wcb + nn * 16 + fr;
    bias[nn] = b2[e * DMODEL + bcol[nn]];
  }
#pragma unroll
  for (int m = 0; m < 8; ++m)
#pragma unroll
    for (int j = 0; j < 4; ++j) {
      const int p = rb * 256 + wrb + m * 16 + kg * 4 + j;
      if (p < n) {
        const int entry = bucket[c * NTOK + p];
        const float s = topks[entry];
        float* orow = out + (size_t)(entry >> 1) * DMODEL;
        if (kbit == 0) {
#pragma unroll
          for (int nn = 0; nn < 4; ++nn)
            orow[bcol[nn]] = s * (acc[m][nn][j] + bias[nn]);
        } else {
#pragma unroll
          for (int nn = 0; nn < 4; ++nn)
            orow[bcol[nn]] += s * (acc[m][nn][j] + bias[nn]);
        }
      }
    }
}

extern "C" void kernel_launch(void* const* d_in, const int* in_sizes, int n_in,
                              void* d_out, int out_size, void* d_ws, size_t ws_size,
                              hipStream_t stream)
{
  const float* x  = (const float*)d_in[0];
  const float* gw = (const float*)d_in[1];
  const float* gb = (const float*)d_in[2];
  const float* w1 = (const float*)d_in[3];
  const float* b1 = (const float*)d_in[4];
  const float* w2 = (const float*)d_in[5];
  const float* b2 = (const float*)d_in[6];
  float* out = (float*)d_out;
  char*  ws  = (char*)d_ws;

  if (ws_size < WS_END) return;  // scratch too small: bail cleanly (validation will flag)

  int*   cnt    = (int*)(ws + WS_CNT);
  int*   offs   = (int*)(ws + WS_OFFS);
  int*   bucket = (int*)(ws + WS_BUCKET);
  float* topks  = (float*)(ws + WS_TOPKS);
  bf16*  xb     = (bf16*)(ws + WS_XB);
  bf16*  w1t    = (bf16*)(ws + WS_W1T);
  bf16*  w2t    = (bf16*)(ws + WS_W2T);
  bf16*  Hbuf   = (bf16*)(ws + WS_H);

  hipMemsetAsync(cnt, 0, NCLS * sizeof(int), stream);

  gate_kernel<<<NTOK / 64, 256, 0, stream>>>(x, gw, gb, cnt, bucket, topks, xb);
  scan_kernel<<<1, 64, 0, stream>>>(cnt, offs);
  cvt_wt_kernel<<<dim3(1024, NEXP), 256, 0, stream>>>(w1, w1t);
  cvt_wt_kernel<<<dim3(1024, NEXP), 256, 0, stream>>>(w2, w2t);
  gemm1_kernel<<<dim3(NCLS * 128, 4), 512, 0, stream>>>(xb, w1t, b1, cnt, offs, bucket, Hbuf);
  gemm2_kernel<<<dim3(NEXP * 128, 4), 512, 0, stream>>>(Hbuf, w2t, b2, cnt, offs, bucket, topks, out, 0);
  gemm2_kernel<<<dim3(NEXP * 128, 4), 512, 0, stream>>>(Hbuf, w2t, b2, cnt, offs, bucket, topks, out, 1);
}

// Round 5
// 756.957 us; speedup vs baseline: 1.4665x; 1.4665x over previous
//
#include <hip/hip_runtime.h>
#include <hip/hip_bf16.h>
#include <stdint.h>

// Sparse MoE FFN: N=32768 tokens, D=H=1024, E=8, top-2, fp32 in/out.
// Pipeline: fp32 gate+top2 (LDS bucketing into 16 (expert,k) classes, fused
// x->bf16) -> bf16 MFMA GEMM1 (relu) -> GEMM2a (k=0, plain store = full out
// coverage) -> GEMM2b (k=1, unique-writer non-atomic RMW add).
// GEMMs: 128x128 tile, 4 waves, 3-buffer LDS (48 KB), depth-2 prefetch with
// counted s_waitcnt vmcnt(4) + raw s_barrier (T4: never drain to 0 mid-loop),
// XCD-chunked swizzle + 4rb x 8cb L2 supertiles.

#define NTOK  32768
#define DMODEL 1024
#define HDIM   1024
#define NEXP      8
#define NCLS     16   // (expert, k) classes
#define BKT      32   // K per LDS tile
#define NT       (DMODEL / BKT)   // 32 K-steps

typedef __bf16 bf16;
typedef __bf16 bf16x4 __attribute__((ext_vector_type(4)));
typedef __bf16 bf16x8 __attribute__((ext_vector_type(8)));
typedef float  f32x4  __attribute__((ext_vector_type(4)));

// ---- workspace layout (bytes), identical to round 3 (known to fit) ----
static constexpr size_t WS_CNT    = 0;                                        // 16 int
static constexpr size_t WS_OFFS   = 256;                                      // 16 int
static constexpr size_t WS_BUCKET = 512;                                      // [NCLS][NTOK] int (entry = tok*2+k)
static constexpr size_t WS_TOPKS  = WS_BUCKET + (size_t)NCLS * NTOK * 4;      // [NTOK*2] float
static constexpr size_t WS_XB     = WS_TOPKS + (size_t)NTOK * 2 * 4;          // x in bf16 [NTOK][D]
static constexpr size_t WS_W1T    = WS_XB  + (size_t)NTOK * DMODEL * 2;       // w1^T bf16 [E][H][D]
static constexpr size_t WS_W2T    = WS_W1T + (size_t)NEXP * DMODEL * HDIM * 2;// w2^T bf16 [E][D][H]
static constexpr size_t WS_H      = WS_W2T + (size_t)NEXP * HDIM * DMODEL * 2;// H bf16 [2N+128][H]
static constexpr size_t WS_END    = WS_H   + (size_t)(2 * NTOK + 128) * HDIM * 2; // ~227 MiB

// async global->LDS, 16B per lane. LDS dest is wave-uniform base + lane*16.
__device__ __forceinline__ void gload16(const void* g, void* l) {
  __builtin_amdgcn_global_load_lds(
      (const __attribute__((address_space(1))) unsigned int*)(uintptr_t)g,
      (__attribute__((address_space(3))) unsigned int*)(uintptr_t)l,
      16, 0, 0);
}

// ---------------- gating: fp32 scores, exact top-2, LDS-aggregated buckets ----
__global__ __launch_bounds__(256) void gate_kernel(
    const float* __restrict__ x, const float* __restrict__ gw,
    const float* __restrict__ gb, int* __restrict__ cnt,
    int* __restrict__ bucket, float* __restrict__ topks,
    bf16* __restrict__ xb)
{
  __shared__ int lcnt[NCLS];
  __shared__ int lbase[NCLS];
  __shared__ short ti_i1[64], ti_i2[64], ti_r1[64], ti_r2[64];

  const int t = threadIdx.x;
  if (t < NCLS) lcnt[t] = 0;
  __syncthreads();

  const int lane = t & 63;
  const int wv   = t >> 6;
  const int t0   = blockIdx.x * 64;

  for (int i = 0; i < 16; ++i) {
    const int tt  = wv * 16 + i;
    const int tok = t0 + tt;
    const float4* xr4 = (const float4*)(x + (size_t)tok * DMODEL);
    bf16x4*       xbr = (bf16x4*)(xb + (size_t)tok * DMODEL);

    float sc[NEXP];
#pragma unroll
    for (int e = 0; e < NEXP; ++e) sc[e] = 0.f;

#pragma unroll
    for (int it = 0; it < 4; ++it) {
      const int q = it * 64 + lane;          // float4 index within the row
      float4 v = xr4[q];
      bf16x4 o = { (bf16)v.x, (bf16)v.y, (bf16)v.z, (bf16)v.w };
      xbr[q] = o;                            // fused fp32->bf16 conversion
      const float* g = gw + (size_t)q * 4 * NEXP;
      const float vv[4] = { v.x, v.y, v.z, v.w };
#pragma unroll
      for (int j = 0; j < 4; ++j)
#pragma unroll
        for (int e = 0; e < NEXP; ++e)
          sc[e] += vv[j] * g[j * NEXP + e];
    }
#pragma unroll
    for (int e = 0; e < NEXP; ++e) {
      float a = sc[e];
#pragma unroll
      for (int off = 32; off; off >>= 1) a += __shfl_xor(a, off);
      sc[e] = a + gb[e];
    }

    if (lane == 0) {
      // strict > keeps the lowest index on ties == lax.top_k semantics
      int i1 = 0; float s1 = sc[0];
#pragma unroll
      for (int e = 1; e < NEXP; ++e) if (sc[e] > s1) { s1 = sc[e]; i1 = e; }
      int i2 = (i1 == 0) ? 1 : 0; float s2 = sc[i2];
#pragma unroll
      for (int e = 0; e < NEXP; ++e)
        if (e != i1 && sc[e] > s2) { s2 = sc[e]; i2 = e; }
      ti_i1[tt] = (short)i1; ti_r1[tt] = (short)atomicAdd(&lcnt[i1 * 2 + 0], 1);
      ti_i2[tt] = (short)i2; ti_r2[tt] = (short)atomicAdd(&lcnt[i2 * 2 + 1], 1);
      topks[tok * 2]     = s1;
      topks[tok * 2 + 1] = s2;
    }
  }
  __syncthreads();
  if (t < NCLS) lbase[t] = atomicAdd(&cnt[t], lcnt[t]);
  __syncthreads();
  if (t < 128) {
    const int tt = t >> 1, k = t & 1;
    const int c  = k ? (ti_i2[tt] * 2 + 1) : (ti_i1[tt] * 2);
    const int r  = k ? ti_r2[tt] : ti_r1[tt];
    bucket[c * NTOK + lbase[c] + r] = (t0 + tt) * 2 + k;
  }
}

__global__ void scan_kernel(const int* __restrict__ cnt, int* __restrict__ offs) {
  if (threadIdx.x == 0) {
    int r = 0;
    for (int c = 0; c < NCLS; ++c) { offs[c] = r; r += cnt[c]; }
  }
}

// w[e][k][n] fp32 -> wt[e][n][k] bf16 (transpose so GEMM B-frags are K-contiguous)
__global__ __launch_bounds__(256) void cvt_wt_kernel(
    const float* __restrict__ w, bf16* __restrict__ wt)
{
  __shared__ float tile[32][33];
  const int e  = blockIdx.y;
  const int tk = (blockIdx.x >> 5) * 32;  // source row (k) base
  const int tn = (blockIdx.x & 31) * 32;  // source col (n) base
  const int r  = threadIdx.x >> 3, c4 = (threadIdx.x & 7) * 4;
  const float* we = w + (size_t)e * DMODEL * HDIM;
  float4 v = *(const float4*)&we[(size_t)(tk + r) * 1024 + tn + c4];
  tile[r][c4 + 0] = v.x; tile[r][c4 + 1] = v.y;
  tile[r][c4 + 2] = v.z; tile[r][c4 + 3] = v.w;
  __syncthreads();
  bf16x4 o = { (bf16)tile[c4 + 0][r], (bf16)tile[c4 + 1][r],
               (bf16)tile[c4 + 2][r], (bf16)tile[c4 + 3][r] };
  *(bf16x4*)&wt[(size_t)e * DMODEL * HDIM + (size_t)(tn + r) * 1024 + tk + c4] = o;
}

// ---- 128x128 K-loop pieces: 3-buffer, depth-2 prefetch, counted vmcnt ----
// 4 waves = 2M x 2N, per-wave 64x64 out. A/B LDS tiles [128][32] bf16 = 8 KB
// each; x3 buffers = 48 KB total -> 3 blocks/CU.

#define GEMM_STAGE(B, KO)                                                     \
  do {                                                                        \
    gload16(aPtr0 + (KO), &As[B][t * 8]);                                     \
    gload16(aPtr1 + (KO), &As[B][2048 + t * 8]);                              \
    gload16(bPtr0 + (KO), &Bs[B][t * 8]);                                     \
    gload16(bPtr1 + (KO), &Bs[B][2048 + t * 8]);                              \
  } while (0)

#define GEMM_COMPUTE(B)                                                       \
  do {                                                                        \
    bf16x8 afr[4], bfr[4];                                                    \
    _Pragma("unroll")                                                         \
    for (int m = 0; m < 4; ++m)                                               \
      afr[m] = *(const bf16x8*)&As[B][(wr + m * 16 + fr) * BKT + kg * 8];     \
    _Pragma("unroll")                                                         \
    for (int nn = 0; nn < 4; ++nn)                                            \
      bfr[nn] = *(const bf16x8*)&Bs[B][(wc + nn * 16 + fr) * BKT + kg * 8];   \
    _Pragma("unroll")                                                         \
    for (int m = 0; m < 4; ++m)                                               \
      _Pragma("unroll")                                                       \
      for (int nn = 0; nn < 4; ++nn)                                          \
        acc[m][nn] = __builtin_amdgcn_mfma_f32_16x16x32_bf16(                 \
            afr[m], bfr[nn], acc[m][nn], 0, 0, 0);                            \
  } while (0)

// One K-step. CB/SB are buffer literals; WAIT4 = counted wait (1) vs drain (0);
// DO_STAGE issues prefetch of K-offset SKO into SB.
#define K_ITER(CB, SB, SKO, WAIT4, DO_STAGE)                                  \
  do {                                                                        \
    if (WAIT4) asm volatile("s_waitcnt vmcnt(4)" ::: "memory");               \
    else       asm volatile("s_waitcnt vmcnt(0)" ::: "memory");               \
    __builtin_amdgcn_sched_barrier(0);                                        \
    __builtin_amdgcn_s_barrier();                                             \
    __builtin_amdgcn_sched_barrier(0);                                        \
    GEMM_COMPUTE(CB);                                                         \
    if (DO_STAGE) GEMM_STAGE(SB, (SKO));                                      \
  } while (0)

// ---------------- GEMM1: H = relu(X[bucket] @ W1 + b1), bf16 out ----------------
__global__ __launch_bounds__(256, 3) void gemm1_kernel(
    const bf16* __restrict__ xb, const bf16* __restrict__ w1t,
    const float* __restrict__ b1, const int* __restrict__ cnt,
    const int* __restrict__ offs, const int* __restrict__ bucket,
    bf16* __restrict__ Hbuf)
{
  // XCD-chunked swizzle (bijective: 32768 % 8 == 0), then per-class
  // 4rb x 8cb supertiles with cb fastest -> L2/L3 window ~3 MB.
  const int bid   = (int)blockIdx.x;
  const int swz   = (bid & 7) * (NCLS * 2048 / 8) + (bid >> 3);
  const int c     = swz >> 11;              // class (e,k)
  const int e     = c >> 1;
  const int inner = swz & 2047;
  const int rb    = ((inner >> 5) << 2) | (inner & 3);
  const int cb    = (inner >> 2) & 7;
  const int n     = cnt[c];
  if (rb * 128 >= n) return;

  __shared__ bf16 As[3][128 * BKT];
  __shared__ bf16 Bs[3][128 * BKT];

  const int t  = threadIdx.x;
  const int sr = t >> 2, sc8 = (t & 3) * 8;
  int p1 = rb * 128 + sr;      if (p1 >= n) p1 = n - 1;
  int p2 = rb * 128 + 64 + sr; if (p2 >= n) p2 = n - 1;
  const int ent1 = bucket[c * NTOK + p1];
  const int ent2 = bucket[c * NTOK + p2];
  const bf16* aPtr0 = xb + (size_t)(ent1 >> 1) * DMODEL + sc8;   // gathered rows
  const bf16* aPtr1 = xb + (size_t)(ent2 >> 1) * DMODEL + sc8;
  const bf16* bPtr0 = w1t + (size_t)e * DMODEL * HDIM
                    + (size_t)(cb * 128 + sr) * DMODEL + sc8;
  const bf16* bPtr1 = bPtr0 + (size_t)64 * DMODEL;

  const int lane = t & 63, wid = t >> 6;
  const int wr = (wid >> 1) * 64, wc = (wid & 1) * 64;
  const int fr = lane & 15, kg = lane >> 4;

  f32x4 acc[4][4];
#pragma unroll
  for (int m = 0; m < 4; ++m)
#pragma unroll
    for (int nn = 0; nn < 4; ++nn) acc[m][nn] = (f32x4){0.f, 0.f, 0.f, 0.f};

  // prologue: depth-2 prefetch (8 loads/thread in flight)
  GEMM_STAGE(0, 0);
  GEMM_STAGE(1, BKT);
  // steady state: t = 0..NT-3 in triples (NT=32 -> t=0..29)
  for (int kt = 0; kt < NT - 2; kt += 3) {
    K_ITER(0, 2, (kt + 2) * BKT, 1, 1);
    K_ITER(1, 0, (kt + 3) * BKT, 1, 1);
    K_ITER(2, 1, (kt + 4) * BKT, 1, 1);
  }
  K_ITER(0, 0, 0, 1, 0);   // t = 30: compute buf 0, nothing left to stage
  K_ITER(1, 0, 0, 0, 0);   // t = 31: final drain + compute buf 1

  // epilogue: bias + relu -> H[slot][col] bf16. C/D: col=lane&15, row=kg*4+reg.
  const int slot0 = offs[c];
  float bias[4]; int bcol[4];
#pragma unroll
  for (int nn = 0; nn < 4; ++nn) {
    bcol[nn] = cb * 128 + wc + nn * 16 + fr;
    bias[nn] = b1[e * HDIM + bcol[nn]];
  }
#pragma unroll
  for (int m = 0; m < 4; ++m)
#pragma unroll
    for (int j = 0; j < 4; ++j) {
      const int p = rb * 128 + wr + m * 16 + kg * 4 + j;
      if (p < n) {
        bf16* hrow = Hbuf + (size_t)(slot0 + p) * HDIM;
#pragma unroll
        for (int nn = 0; nn < 4; ++nn) {
          float v = acc[m][nn][j] + bias[nn];
          hrow[bcol[nn]] = (bf16)(v > 0.f ? v : 0.f);
        }
      }
    }
}

// -------- GEMM2: kbit=0: out[tok] = s*(H@W2+b2) (full coverage, plain store);
// kbit=1: out[tok] += ... (unique writer per (tok,col) within the launch). ----
__global__ __launch_bounds__(256, 3) void gemm2_kernel(
    const bf16* __restrict__ Hbuf, const bf16* __restrict__ w2t,
    const float* __restrict__ b2, const int* __restrict__ cnt,
    const int* __restrict__ offs, const int* __restrict__ bucket,
    const float* __restrict__ topks, float* __restrict__ out, int kbit)
{
  const int bid   = (int)blockIdx.x;
  const int swz   = (bid & 7) * (NEXP * 2048 / 8) + (bid >> 3);
  const int e     = swz >> 11;
  const int c     = e * 2 + kbit;           // class
  const int inner = swz & 2047;
  const int rb    = ((inner >> 5) << 2) | (inner & 3);
  const int cb    = (inner >> 2) & 7;
  const int n     = cnt[c];
  if (rb * 128 >= n) return;

  __shared__ bf16 As[3][128 * BKT];
  __shared__ bf16 Bs[3][128 * BKT];

  const int t  = threadIdx.x;
  const int sr = t >> 2, sc8 = (t & 3) * 8;
  const int slot0 = offs[c];
  int p1 = rb * 128 + sr;      if (p1 >= n) p1 = n - 1;
  int p2 = rb * 128 + 64 + sr; if (p2 >= n) p2 = n - 1;
  const bf16* aPtr0 = Hbuf + (size_t)(slot0 + p1) * HDIM + sc8;
  const bf16* aPtr1 = Hbuf + (size_t)(slot0 + p2) * HDIM + sc8;
  const bf16* bPtr0 = w2t + (size_t)e * HDIM * DMODEL
                    + (size_t)(cb * 128 + sr) * HDIM + sc8;
  const bf16* bPtr1 = bPtr0 + (size_t)64 * HDIM;

  const int lane = t & 63, wid = t >> 6;
  const int wr = (wid >> 1) * 64, wc = (wid & 1) * 64;
  const int fr = lane & 15, kg = lane >> 4;

  f32x4 acc[4][4];
#pragma unroll
  for (int m = 0; m < 4; ++m)
#pragma unroll
    for (int nn = 0; nn < 4; ++nn) acc[m][nn] = (f32x4){0.f, 0.f, 0.f, 0.f};

  GEMM_STAGE(0, 0);
  GEMM_STAGE(1, BKT);
  for (int kt = 0; kt < NT - 2; kt += 3) {
    K_ITER(0, 2, (kt + 2) * BKT, 1, 1);
    K_ITER(1, 0, (kt + 3) * BKT, 1, 1);
    K_ITER(2, 1, (kt + 4) * BKT, 1, 1);
  }
  K_ITER(0, 0, 0, 1, 0);
  K_ITER(1, 0, 0, 0, 0);

  float bias[4]; int bcol[4];
#pragma unroll
  for (int nn = 0; nn < 4; ++nn) {
    bcol[nn] = cb * 128 + wc + nn * 16 + fr;
    bias[nn] = b2[e * DMODEL + bcol[nn]];
  }
#pragma unroll
  for (int m = 0; m < 4; ++m)
#pragma unroll
    for (int j = 0; j < 4; ++j) {
      const int p = rb * 128 + wr + m * 16 + kg * 4 + j;
      if (p < n) {
        const int entry = bucket[c * NTOK + p];
        const float s = topks[entry];
        float* orow = out + (size_t)(entry >> 1) * DMODEL;
        if (kbit == 0) {
#pragma unroll
          for (int nn = 0; nn < 4; ++nn)
            orow[bcol[nn]] = s * (acc[m][nn][j] + bias[nn]);
        } else {
#pragma unroll
          for (int nn = 0; nn < 4; ++nn)
            orow[bcol[nn]] += s * (acc[m][nn][j] + bias[nn]);
        }
      }
    }
}

extern "C" void kernel_launch(void* const* d_in, const int* in_sizes, int n_in,
                              void* d_out, int out_size, void* d_ws, size_t ws_size,
                              hipStream_t stream)
{
  const float* x  = (const float*)d_in[0];
  const float* gw = (const float*)d_in[1];
  const float* gb = (const float*)d_in[2];
  const float* w1 = (const float*)d_in[3];
  const float* b1 = (const float*)d_in[4];
  const float* w2 = (const float*)d_in[5];
  const float* b2 = (const float*)d_in[6];
  float* out = (float*)d_out;
  char*  ws  = (char*)d_ws;

  if (ws_size < WS_END) return;  // scratch too small: bail cleanly (validation will flag)

  int*   cnt    = (int*)(ws + WS_CNT);
  int*   offs   = (int*)(ws + WS_OFFS);
  int*   bucket = (int*)(ws + WS_BUCKET);
  float* topks  = (float*)(ws + WS_TOPKS);
  bf16*  xb     = (bf16*)(ws + WS_XB);
  bf16*  w1t    = (bf16*)(ws + WS_W1T);
  bf16*  w2t    = (bf16*)(ws + WS_W2T);
  bf16*  Hbuf   = (bf16*)(ws + WS_H);

  hipMemsetAsync(cnt, 0, NCLS * sizeof(int), stream);

  gate_kernel<<<NTOK / 64, 256, 0, stream>>>(x, gw, gb, cnt, bucket, topks, xb);
  scan_kernel<<<1, 64, 0, stream>>>(cnt, offs);
  cvt_wt_kernel<<<dim3(1024, NEXP), 256, 0, stream>>>(w1, w1t);
  cvt_wt_kernel<<<dim3(1024, NEXP), 256, 0, stream>>>(w2, w2t);
  gemm1_kernel<<<NCLS * 2048, 256, 0, stream>>>(xb, w1t, b1, cnt, offs, bucket, Hbuf);
  gemm2_kernel<<<NEXP * 2048, 256, 0, stream>>>(Hbuf, w2t, b2, cnt, offs, bucket, topks, out, 0);
  gemm2_kernel<<<NEXP * 2048, 256, 0, stream>>>(Hbuf, w2t, b2, cnt, offs, bucket, topks, out, 1);
}